// Round 5
// baseline (549.889 us; speedup 1.0000x reference)
//
#include <hip/hip_runtime.h>
#include <hip/hip_bf16.h>

// GraphSAGE-LSTM aggregator, MI355X (gfx950).  B=16384, T=25, D=128, U=128.
// R5 changes vs R3 (R3 measured: 442us, FETCH 1.31GB, BW-bound at 3.35TB/s on
// W-fragment L2 misses -- 512 blocks' gather streams thrash the 4MB per-XCD
// L2 and evict the 128KB W-frag working set every step):
//  - feature gathers + out stores are NON-TEMPORAL (MUBUF nt): gather lines
//    are evict-first in L2, W fragments stay L2-resident -> per-step W-frag
//    reloads become L2 hits, not HBM/L3 fetches
//  - otherwise identical to R3 (512 blocks x 32 rows, 2 blocks/CU)
// ws layout (bf16 elems):
//   [0, 147456)            weight fragments (W, U, node_weights)
//   [262144, 13062144)     features as bf16 (100000 x 128)
// ws_size needed: 26.2 MB.

typedef __bf16 bf16;
typedef __bf16 bf16x8 __attribute__((ext_vector_type(8)));
typedef float f32x4 __attribute__((ext_vector_type(4)));

#define FEATS_OFF 262144

__device__ __forceinline__ float fast_sig(float x) {
  float e = __builtin_amdgcn_exp2f(-1.442695041f * x);
  return __builtin_amdgcn_rcpf(1.0f + e);
}
__device__ __forceinline__ float fast_tanh(float x) {
  float e = __builtin_amdgcn_exp2f(-2.885390082f * x);
  return (1.0f - e) * __builtin_amdgcn_rcpf(1.0f + e);
}
__device__ __forceinline__ f32x4 splat4(float x) {
  f32x4 v; v[0] = x; v[1] = x; v[2] = x; v[3] = x; return v;
}
__device__ __forceinline__ bf16x8 pack8(float4 a, float4 b) {
  bf16x8 v;
  v[0] = (bf16)a.x; v[1] = (bf16)a.y; v[2] = (bf16)a.z; v[3] = (bf16)a.w;
  v[4] = (bf16)b.x; v[5] = (bf16)b.y; v[6] = (bf16)b.z; v[7] = (bf16)b.w;
  return v;
}

// ---------------- prep A: fragment-pack weights into ws (bf16) ----------------
// Fragment semantics (B operand of 16x16x32): lane supplies
//   B[k = kt*32 + (lane>>4)*8 + j][col], col = g*128 + w*16 + (lane&15).
__global__ void prep_kernel(const float* __restrict__ W, const float* __restrict__ U,
                            const float* __restrict__ NW, bf16* __restrict__ ws) {
  int idx = blockIdx.x * 256 + threadIdx.x;  // 576*256 = 147456 exactly
  if (idx < 131072) {
    const float* __restrict__ src = (idx < 65536) ? W : U;
    int r = idx & 65535;
    int f = r >> 9, lane = (r >> 3) & 63, j = r & 7;
    int kt = f & 3, g = (f >> 2) & 3, w = f >> 4;
    int k = kt * 32 + (lane >> 4) * 8 + j;
    int col = g * 128 + w * 16 + (lane & 15);
    ws[idx] = (bf16)src[k * 512 + col];
  } else {
    int r = idx - 131072;
    int f = r >> 9, lane = (r >> 3) & 63, j = r & 7;
    int kt = f & 3, w = f >> 2;
    int k = kt * 32 + (lane >> 4) * 8 + j;
    int col = w * 16 + (lane & 15);
    ws[idx] = (bf16)NW[k * 128 + col];
  }
}

// ---------------- prep B: features fp32 -> bf16 (streaming) ----------------
__global__ void prep_feats(const float4* __restrict__ in, bf16x8* __restrict__ out) {
  int i = blockIdx.x * 256 + threadIdx.x;
  int stride = gridDim.x * 256;
  for (; i < 1600000; i += stride) {  // 100000*128/8
    float4 a = in[2 * i], b = in[2 * i + 1];
    __builtin_nontemporal_store(pack8(a, b), out + i);
  }
}

// ---------------- fused LSTM aggregator ----------------
__global__ __launch_bounds__(512, 4)
void lstm_kernel(const int* __restrict__ node, const int* __restrict__ neigh,
                 const float* __restrict__ bias, const bf16* __restrict__ wsf,
                 float* __restrict__ out) {
  __shared__ char xb[8192];  // x tile [32 rows][128] bf16, XOR-swizzled
  __shared__ char hb[8192];  // h tile [32 rows][128] bf16, XOR-swizzled

  const int tid  = threadIdx.x;
  const int lane = tid & 63;
  const int wv   = tid >> 6;       // wave id = unit group (16 units each)
  const int l15  = lane & 15;
  const int lhi  = lane >> 4;
  const int b0   = blockIdx.x * 32;
  const bf16* __restrict__ fb = wsf + FEATS_OFF;

  // Persistent U fragments in registers (64 VGPR), loaded once.
  bf16x8 uf[4][4];
#pragma unroll
  for (int g = 0; g < 4; ++g)
#pragma unroll
    for (int kt = 0; kt < 4; ++kt)
      uf[g][kt] = *(const bf16x8*)(wsf + 65536 + (((wv * 4 + g) * 4 + kt) << 9) + (lane << 3));

  float bb[4];
#pragma unroll
  for (int g = 0; g < 4; ++g) bb[g] = bias[g * 128 + wv * 16 + l15];

  f32x4 cc[2];  // cell state: row = m*16 + lhi*4 + r, unit = wv*16 + l15
#pragma unroll
  for (int m = 0; m < 2; ++m) cc[m] = splat4(0.0f);

  // Gather mapping: thread covers row gr, 16 consecutive bytes (8 bf16).
  const int gr = tid >> 4;          // 0..31
  const int gq = tid & 15;          // 16B chunk within row
  const int xsw = (gr & 7) << 4;
  const int xbase = gr * 256 + gq * 16;
  const int rbase = (b0 + gr) * 25;

  // x_0
  {
    int ni = neigh[rbase];
    *(bf16x8*)(xb + (xbase ^ xsw)) =
        __builtin_nontemporal_load((const bf16x8*)(fb + (size_t)ni * 128 + gq * 8));
  }
  int ni_next = neigh[rbase + 1];
  __syncthreads();

  f32x4 acc[4][2];                 // [gate][Mtile]
  const int asw = (l15 & 7) << 4;  // A-frag row swizzle (row&7 == l15&7)
  bf16x8 wf[4];                    // current-kt W fragments (pipelined)

  auto preload_wf0 = [&]() {
#pragma unroll
    for (int g = 0; g < 4; ++g)
      wf[g] = *(const bf16x8*)(wsf + (((wv * 4 + g) * 4) << 9) + (lane << 3));
  };

  auto mfma_phase = [&](bool withH) {
#pragma unroll
    for (int kt = 0; kt < 4; ++kt) {
      bf16x8 wfn[4];
      if (kt < 3) {
#pragma unroll
        for (int g = 0; g < 4; ++g)
          wfn[g] = *(const bf16x8*)(wsf + (((wv * 4 + g) * 4 + kt + 1) << 9) + (lane << 3));
      }
      bf16x8 xa[2];
#pragma unroll
      for (int m = 0; m < 2; ++m)
        xa[m] = *(const bf16x8*)(xb + (((m * 16 + l15) * 256 + (kt * 4 + lhi) * 16) ^ asw));
#pragma unroll
      for (int g = 0; g < 4; ++g)
#pragma unroll
        for (int m = 0; m < 2; ++m)
          acc[g][m] = __builtin_amdgcn_mfma_f32_16x16x32_bf16(xa[m], wf[g], acc[g][m], 0, 0, 0);
      if (withH) {
        bf16x8 ha[2];
#pragma unroll
        for (int m = 0; m < 2; ++m)
          ha[m] = *(const bf16x8*)(hb + (((m * 16 + l15) * 256 + (kt * 4 + lhi) * 16) ^ asw));
#pragma unroll
        for (int g = 0; g < 4; ++g)
#pragma unroll
          for (int m = 0; m < 2; ++m)
            acc[g][m] = __builtin_amdgcn_mfma_f32_16x16x32_bf16(ha[m], uf[g][kt], acc[g][m], 0, 0, 0);
      }
      if (kt < 3) {
#pragma unroll
        for (int g = 0; g < 4; ++g) wf[g] = wfn[g];
      }
    }
  };

#pragma unroll 1
  for (int t = 0; t < 24; ++t) {
    int ni = ni_next;
    ni_next = (t < 23) ? neigh[rbase + t + 2] : node[b0 + gr];

    preload_wf0();  // kt0 W frags issued BEFORE gather: no drain at kt0

    bf16x8 pa = __builtin_nontemporal_load((const bf16x8*)(fb + (size_t)ni * 128 + gq * 8));

#pragma unroll
    for (int g = 0; g < 4; ++g) {
      f32x4 bi = splat4(bb[g]);
#pragma unroll
      for (int m = 0; m < 2; ++m) acc[g][m] = bi;
    }

    if (t == 0) mfma_phase(false); else mfma_phase(true);
    __syncthreads();  // all reads of xb/hb done

    *(bf16x8*)(xb + (xbase ^ xsw)) = pa;

#pragma unroll
    for (int m = 0; m < 2; ++m)
#pragma unroll
      for (int r = 0; r < 4; ++r) {
        float iv = fast_sig(acc[0][m][r]);
        float fv = fast_sig(acc[1][m][r]);
        float gv = fast_tanh(acc[2][m][r]);
        float ov = fast_sig(acc[3][m][r]);
        float cv = fv * cc[m][r] + iv * gv;
        cc[m][r] = cv;
        float hv = ov * fast_tanh(cv);
        int row = m * 16 + lhi * 4 + r;
        *(bf16*)(hb + ((row * 256 + (wv * 16 + l15) * 2) ^ ((row & 7) << 4))) = (bf16)hv;
      }
    __syncthreads();  // new x/h visible
  }

  // ----- step 24 (peeled): gather = NODE features (idx pipelined above) -----
  float hl[2][4];
  {
    preload_wf0();
    bf16x8 pa = __builtin_nontemporal_load((const bf16x8*)(fb + (size_t)ni_next * 128 + gq * 8));

#pragma unroll
    for (int g = 0; g < 4; ++g) {
      f32x4 bi = splat4(bb[g]);
#pragma unroll
      for (int m = 0; m < 2; ++m) acc[g][m] = bi;
    }
    mfma_phase(true);
    __syncthreads();

    *(bf16x8*)(xb + (xbase ^ xsw)) = pa;  // node feats

#pragma unroll
    for (int m = 0; m < 2; ++m)
#pragma unroll
      for (int r = 0; r < 4; ++r) {
        float iv = fast_sig(acc[0][m][r]);
        float fv = fast_sig(acc[1][m][r]);
        float gv = fast_tanh(acc[2][m][r]);
        float ov = fast_sig(acc[3][m][r]);
        float cv = fv * cc[m][r] + iv * gv;
        hl[m][r] = ov * fast_tanh(cv);
      }
    __syncthreads();  // node feats visible in xb
  }

  // ----- from_self = node_feat @ node_weights; out = relu((s + h)/2) -----
  {
    bf16x8 nwf[4];
#pragma unroll
    for (int kt = 0; kt < 4; ++kt)
      nwf[kt] = *(const bf16x8*)(wsf + 131072 + ((wv * 4 + kt) << 9) + (lane << 3));
    f32x4 accs[2];
#pragma unroll
    for (int m = 0; m < 2; ++m) accs[m] = splat4(0.0f);
#pragma unroll
    for (int kt = 0; kt < 4; ++kt) {
      bf16x8 xa[2];
#pragma unroll
      for (int m = 0; m < 2; ++m)
        xa[m] = *(const bf16x8*)(xb + (((m * 16 + l15) * 256 + (kt * 4 + lhi) * 16) ^ asw));
#pragma unroll
      for (int m = 0; m < 2; ++m)
        accs[m] = __builtin_amdgcn_mfma_f32_16x16x32_bf16(xa[m], nwf[kt], accs[m], 0, 0, 0);
    }
#pragma unroll
    for (int m = 0; m < 2; ++m)
#pragma unroll
      for (int r = 0; r < 4; ++r) {
        int row = m * 16 + lhi * 4 + r;
        float v = (accs[m][r] + hl[m][r]) * 0.5f;
        __builtin_nontemporal_store(v > 0.0f ? v : 0.0f,
                                    out + (b0 + row) * 128 + wv * 16 + l15);
      }
  }
}

extern "C" void kernel_launch(void* const* d_in, const int* in_sizes, int n_in,
                              void* d_out, int out_size, void* d_ws, size_t ws_size,
                              hipStream_t stream) {
  const float* feats = (const float*)d_in[0];   // 100000 x 128
  const int*   node  = (const int*)d_in[1];     // 16384 x 1
  const int*   neigh = (const int*)d_in[2];     // 16384 x 25
  const float* nw    = (const float*)d_in[3];   // 128 x 128
  const float* W     = (const float*)d_in[4];   // 128 x 512
  const float* U     = (const float*)d_in[5];   // 128 x 512
  const float* b     = (const float*)d_in[6];   // 512
  bf16* ws = (bf16*)d_ws;                       // needs 26.2 MB
  float* out = (float*)d_out;                   // 16384 x 128

  prep_kernel<<<576, 256, 0, stream>>>(W, U, nw, ws);
  prep_feats<<<2048, 256, 0, stream>>>((const float4*)feats, (bf16x8*)(ws + FEATS_OFF));
  lstm_kernel<<<512, 512, 0, stream>>>(node, neigh, b, ws, out);
}

// Round 6
// 454.487 us; speedup vs baseline: 1.2099x; 1.2099x over previous
//
#include <hip/hip_runtime.h>
#include <hip/hip_bf16.h>

// GraphSAGE-LSTM aggregator, MI355X (gfx950).  B=16384, T=25, D=128, U=128.
// R6 changes vs R5 (R3/R5 diagnosed: launch_bounds(512,4) forced spill of
// ~50 regs of hot-loop state -> 1.31GB deterministic scratch traffic; even
// R1/R2 carried minor spills. U-in-registers (64 VGPR) is what makes >8
// waves/CU impossible without spilling):
//  - U fragments moved to LDS (128 KB, shared per block, conflict-free
//    ds_read_b128) -- per-thread state drops to ~115 regs, genuinely fits
//    the 128-reg budget: NO spills at 4 waves/SIMD
//  - 1024-thread blocks (16 waves = 8 unit-groups x 2 row-halves), 64 rows,
//    256 blocks = 1 block/CU, 16 waves/CU (Occ 50%)
//  - LDS = 128K (U frags) + 16K (x tile) + 16K (h tile) = 160 KiB exactly
//  - W frags: per-kt loads, ALL issued before the step's gather -> in-order
//    vmcnt waits for W never expose gather latency; gather retires during
//    gates+barrier
// ws layout (bf16 elems):
//   [0, 147456)            weight fragments (W, U, node_weights)
//   [262144, 13062144)     features as bf16 (100000 x 128)
// ws_size needed: 26.2 MB.

typedef __bf16 bf16;
typedef __bf16 bf16x8 __attribute__((ext_vector_type(8)));
typedef float f32x4 __attribute__((ext_vector_type(4)));

#define FEATS_OFF 262144

__device__ __forceinline__ float fast_sig(float x) {
  float e = __builtin_amdgcn_exp2f(-1.442695041f * x);
  return __builtin_amdgcn_rcpf(1.0f + e);
}
__device__ __forceinline__ float fast_tanh(float x) {
  float e = __builtin_amdgcn_exp2f(-2.885390082f * x);
  return (1.0f - e) * __builtin_amdgcn_rcpf(1.0f + e);
}
__device__ __forceinline__ f32x4 splat4(float x) {
  f32x4 v; v[0] = x; v[1] = x; v[2] = x; v[3] = x; return v;
}
__device__ __forceinline__ bf16x8 pack8(float4 a, float4 b) {
  bf16x8 v;
  v[0] = (bf16)a.x; v[1] = (bf16)a.y; v[2] = (bf16)a.z; v[3] = (bf16)a.w;
  v[4] = (bf16)b.x; v[5] = (bf16)b.y; v[6] = (bf16)b.z; v[7] = (bf16)b.w;
  return v;
}

// ---------------- prep A: fragment-pack weights into ws (bf16) ----------------
// Fragment semantics (B operand of 16x16x32): lane supplies
//   B[k = kt*32 + (lane>>4)*8 + j][col], col = g*128 + ug*16 + (lane&15).
__global__ void prep_kernel(const float* __restrict__ W, const float* __restrict__ U,
                            const float* __restrict__ NW, bf16* __restrict__ ws) {
  int idx = blockIdx.x * 256 + threadIdx.x;  // 576*256 = 147456 exactly
  if (idx < 131072) {
    const float* __restrict__ src = (idx < 65536) ? W : U;
    int r = idx & 65535;
    int f = r >> 9, lane = (r >> 3) & 63, j = r & 7;
    int kt = f & 3, g = (f >> 2) & 3, w = f >> 4;
    int k = kt * 32 + (lane >> 4) * 8 + j;
    int col = g * 128 + w * 16 + (lane & 15);
    ws[idx] = (bf16)src[k * 512 + col];
  } else {
    int r = idx - 131072;
    int f = r >> 9, lane = (r >> 3) & 63, j = r & 7;
    int kt = f & 3, w = f >> 2;
    int k = kt * 32 + (lane >> 4) * 8 + j;
    int col = w * 16 + (lane & 15);
    ws[idx] = (bf16)NW[k * 128 + col];
  }
}

// ---------------- prep B: features fp32 -> bf16 (streaming) ----------------
__global__ void prep_feats(const float4* __restrict__ in, bf16x8* __restrict__ out) {
  int i = blockIdx.x * 256 + threadIdx.x;
  int stride = gridDim.x * 256;
  for (; i < 1600000; i += stride) {  // 100000*128/8
    float4 a = in[2 * i], b = in[2 * i + 1];
    __builtin_nontemporal_store(pack8(a, b), out + i);
  }
}

// ---------------- fused LSTM aggregator ----------------
__global__ __launch_bounds__(1024, 4)
void lstm_kernel(const int* __restrict__ node, const int* __restrict__ neigh,
                 const float* __restrict__ bias, const bf16* __restrict__ wsf,
                 float* __restrict__ out) {
  __shared__ char ub[131072];  // U fragments, frag-linear (copied from ws)
  __shared__ char xb[16384];   // x tile [64 rows][128] bf16, XOR-swizzled
  __shared__ char hb[16384];   // h tile [64 rows][128] bf16, XOR-swizzled

  const int tid  = threadIdx.x;
  const int lane = tid & 63;
  const int wv   = tid >> 6;       // 0..15
  const int ug   = wv & 7;         // unit group: units [ug*16, ug*16+16)
  const int rh   = wv >> 3;        // row half: rows [rh*32, rh*32+32)
  const int l15  = lane & 15;
  const int lhi  = lane >> 4;
  const int b0   = blockIdx.x * 64;
  const bf16* __restrict__ fb = wsf + FEATS_OFF;

  // ---- prologue: fill U-frag LDS (straight 128 KB copy, once per block) ----
#pragma unroll
  for (int i = 0; i < 8; ++i) {
    int k = i * 1024 + tid;  // 8192 chunks of 16 B
    ((bf16x8*)ub)[k] = *(const bf16x8*)(wsf + 65536 + k * 8);
  }

  float bb[4];
#pragma unroll
  for (int g = 0; g < 4; ++g) bb[g] = bias[g * 128 + ug * 16 + l15];

  f32x4 cc[2];  // cell state: row = rh*32 + m*16 + lhi*4 + r, unit = ug*16+l15
#pragma unroll
  for (int m = 0; m < 2; ++m) cc[m] = splat4(0.0f);

  // Gather mapping: thread covers row gr, 16 consecutive bytes (8 bf16).
  const int gr = tid >> 4;          // 0..63
  const int gq = tid & 15;          // 16B chunk within row
  const int xsw = (gr & 7) << 4;
  const int xbase = gr * 256 + gq * 16;
  const int rbase = (b0 + gr) * 25;

  // x_0
  {
    int ni = neigh[rbase];
    *(bf16x8*)(xb + (xbase ^ xsw)) =
        __builtin_nontemporal_load((const bf16x8*)(fb + (size_t)ni * 128 + gq * 8));
  }
  int ni_next = neigh[rbase + 1];
  __syncthreads();

  f32x4 acc[4][2];                 // [gate][Mtile]
  const int asw = (l15 & 7) << 4;  // A-frag row swizzle (row&7 == l15&7)

  // MFMA phase: per kt, 4 W-frag global loads (L2) + 4 U ds_reads + 2 xa
  // (+2 ha) ds_reads + 8 (+8) MFMAs.  All W issued before the gather.
  auto mfma_phase = [&](bool withH) {
#pragma unroll
    for (int kt = 0; kt < 4; ++kt) {
      bf16x8 wf[4], ufr[4];
#pragma unroll
      for (int g = 0; g < 4; ++g) {
        wf[g]  = *(const bf16x8*)(wsf + (((ug * 4 + g) * 4 + kt) << 9) + (lane << 3));
        ufr[g] = *(const bf16x8*)(ub + (((ug * 16 + g * 4 + kt) << 6 | lane) << 4));
      }
      bf16x8 xa[2];
#pragma unroll
      for (int m = 0; m < 2; ++m)
        xa[m] = *(const bf16x8*)(xb + (((rh * 32 + m * 16 + l15) * 256 + (kt * 4 + lhi) * 16) ^ asw));
#pragma unroll
      for (int g = 0; g < 4; ++g)
#pragma unroll
        for (int m = 0; m < 2; ++m)
          acc[g][m] = __builtin_amdgcn_mfma_f32_16x16x32_bf16(xa[m], wf[g], acc[g][m], 0, 0, 0);
      if (withH) {
        bf16x8 ha[2];
#pragma unroll
        for (int m = 0; m < 2; ++m)
          ha[m] = *(const bf16x8*)(hb + (((rh * 32 + m * 16 + l15) * 256 + (kt * 4 + lhi) * 16) ^ asw));
#pragma unroll
        for (int g = 0; g < 4; ++g)
#pragma unroll
          for (int m = 0; m < 2; ++m)
            acc[g][m] = __builtin_amdgcn_mfma_f32_16x16x32_bf16(ha[m], ufr[g], acc[g][m], 0, 0, 0);
      }
    }
  };

#pragma unroll 1
  for (int t = 0; t < 24; ++t) {
    int ni = ni_next;
    ni_next = (t < 23) ? neigh[rbase + t + 2] : node[b0 + gr];

#pragma unroll
    for (int g = 0; g < 4; ++g) {
      f32x4 bi = splat4(bb[g]);
#pragma unroll
      for (int m = 0; m < 2; ++m) acc[g][m] = bi;
    }

    if (t == 0) mfma_phase(false); else mfma_phase(true);

    // gather x_{t+1}: issued AFTER all W loads; retires during gates+barrier
    bf16x8 pa = __builtin_nontemporal_load((const bf16x8*)(fb + (size_t)ni * 128 + gq * 8));

    __syncthreads();  // all reads of xb/hb done

    *(bf16x8*)(xb + (xbase ^ xsw)) = pa;

#pragma unroll
    for (int m = 0; m < 2; ++m)
#pragma unroll
      for (int r = 0; r < 4; ++r) {
        float iv = fast_sig(acc[0][m][r]);
        float fv = fast_sig(acc[1][m][r]);
        float gv = fast_tanh(acc[2][m][r]);
        float ov = fast_sig(acc[3][m][r]);
        float cv = fv * cc[m][r] + iv * gv;
        cc[m][r] = cv;
        float hv = ov * fast_tanh(cv);
        int row = rh * 32 + m * 16 + lhi * 4 + r;
        *(bf16*)(hb + ((row * 256 + (ug * 16 + l15) * 2) ^ ((row & 7) << 4))) = (bf16)hv;
      }
    __syncthreads();  // new x/h visible
  }

  // ----- step 24 (peeled): gather = NODE features (idx pipelined above) -----
  float hl[2][4];
  {
#pragma unroll
    for (int g = 0; g < 4; ++g) {
      f32x4 bi = splat4(bb[g]);
#pragma unroll
      for (int m = 0; m < 2; ++m) acc[g][m] = bi;
    }
    mfma_phase(true);

    bf16x8 pa = __builtin_nontemporal_load((const bf16x8*)(fb + (size_t)ni_next * 128 + gq * 8));

    __syncthreads();

    *(bf16x8*)(xb + (xbase ^ xsw)) = pa;  // node feats

#pragma unroll
    for (int m = 0; m < 2; ++m)
#pragma unroll
      for (int r = 0; r < 4; ++r) {
        float iv = fast_sig(acc[0][m][r]);
        float fv = fast_sig(acc[1][m][r]);
        float gv = fast_tanh(acc[2][m][r]);
        float ov = fast_sig(acc[3][m][r]);
        float cv = fv * cc[m][r] + iv * gv;
        hl[m][r] = ov * fast_tanh(cv);
      }
    __syncthreads();  // node feats visible in xb
  }

  // ----- from_self = node_feat @ node_weights; out = relu((s + h)/2) -----
  {
    f32x4 accs[2];
#pragma unroll
    for (int m = 0; m < 2; ++m) accs[m] = splat4(0.0f);
#pragma unroll
    for (int kt = 0; kt < 4; ++kt) {
      bf16x8 nwf = *(const bf16x8*)(wsf + 131072 + ((ug * 4 + kt) << 9) + (lane << 3));
      bf16x8 xa[2];
#pragma unroll
      for (int m = 0; m < 2; ++m)
        xa[m] = *(const bf16x8*)(xb + (((rh * 32 + m * 16 + l15) * 256 + (kt * 4 + lhi) * 16) ^ asw));
#pragma unroll
      for (int m = 0; m < 2; ++m)
        accs[m] = __builtin_amdgcn_mfma_f32_16x16x32_bf16(xa[m], nwf, accs[m], 0, 0, 0);
    }
#pragma unroll
    for (int m = 0; m < 2; ++m)
#pragma unroll
      for (int r = 0; r < 4; ++r) {
        int row = rh * 32 + m * 16 + lhi * 4 + r;
        float v = (accs[m][r] + hl[m][r]) * 0.5f;
        __builtin_nontemporal_store(v > 0.0f ? v : 0.0f,
                                    out + (b0 + row) * 128 + ug * 16 + l15);
      }
  }
}

extern "C" void kernel_launch(void* const* d_in, const int* in_sizes, int n_in,
                              void* d_out, int out_size, void* d_ws, size_t ws_size,
                              hipStream_t stream) {
  const float* feats = (const float*)d_in[0];   // 100000 x 128
  const int*   node  = (const int*)d_in[1];     // 16384 x 1
  const int*   neigh = (const int*)d_in[2];     // 16384 x 25
  const float* nw    = (const float*)d_in[3];   // 128 x 128
  const float* W     = (const float*)d_in[4];   // 128 x 512
  const float* U     = (const float*)d_in[5];   // 128 x 512
  const float* b     = (const float*)d_in[6];   // 512
  bf16* ws = (bf16*)d_ws;                       // needs 26.2 MB
  float* out = (float*)d_out;                   // 16384 x 128

  prep_kernel<<<576, 256, 0, stream>>>(W, U, nw, ws);
  prep_feats<<<2048, 256, 0, stream>>>((const float4*)feats, (bf16x8*)(ws + FEATS_OFF));
  lstm_kernel<<<256, 1024, 0, stream>>>(node, neigh, b, ws, out);
}

// Round 7
// 262.571 us; speedup vs baseline: 2.0942x; 1.7309x over previous
//
#include <hip/hip_runtime.h>
#include <hip/hip_bf16.h>

// GraphSAGE-LSTM aggregator, MI355X (gfx950).  B=16384, T=25, D=128, U=128.
// R7 changes vs R6 (R6 diagnosed: 1024-thr block forces <=128 reg/thread ->
// ~80MB spill-store traffic (WRITE 88MB vs 8.4MB out); rh-duplicated W reads
// doubled W L2 demand to 1.64GB -> ~490MB misses; gather issued after MFMA
// phase -> L3 latency exposed in barrier window every step):
//  - 512-thr blocks, 8 waves = 8 unit groups (NO rh duplication), 64 rows,
//    4 M-tiles/wave (acc 64 regs), 256 blocks = 1 block/CU
//  - __launch_bounds__(512,2): 256-reg budget -> zero spills (state ~200)
//  - U in LDS (128KB) + x/h tiles (16KB each) = 160 KiB exactly
//  - per step: ALL 16 W-frag loads issued first, then gather, then
//    sched_barrier(0)-pinned; counted vmcnt waits for W keep the gather in
//    flight under the whole MFMA phase (oldest-first vmcnt semantics)
// ws layout (bf16 elems):
//   [0, 147456)            weight fragments (W, U, node_weights)
//   [262144, 13062144)     features as bf16 (100000 x 128)
// ws_size needed: 26.2 MB.

typedef __bf16 bf16;
typedef __bf16 bf16x8 __attribute__((ext_vector_type(8)));
typedef float f32x4 __attribute__((ext_vector_type(4)));

#define FEATS_OFF 262144

__device__ __forceinline__ float fast_sig(float x) {
  float e = __builtin_amdgcn_exp2f(-1.442695041f * x);
  return __builtin_amdgcn_rcpf(1.0f + e);
}
__device__ __forceinline__ float fast_tanh(float x) {
  float e = __builtin_amdgcn_exp2f(-2.885390082f * x);
  return (1.0f - e) * __builtin_amdgcn_rcpf(1.0f + e);
}
__device__ __forceinline__ f32x4 splat4(float x) {
  f32x4 v; v[0] = x; v[1] = x; v[2] = x; v[3] = x; return v;
}
__device__ __forceinline__ bf16x8 pack8(float4 a, float4 b) {
  bf16x8 v;
  v[0] = (bf16)a.x; v[1] = (bf16)a.y; v[2] = (bf16)a.z; v[3] = (bf16)a.w;
  v[4] = (bf16)b.x; v[5] = (bf16)b.y; v[6] = (bf16)b.z; v[7] = (bf16)b.w;
  return v;
}

// ---------------- prep A: fragment-pack weights into ws (bf16) ----------------
// Fragment semantics (B operand of 16x16x32): lane supplies
//   B[k = kt*32 + (lane>>4)*8 + j][col], col = g*128 + ug*16 + (lane&15).
__global__ void prep_kernel(const float* __restrict__ W, const float* __restrict__ U,
                            const float* __restrict__ NW, bf16* __restrict__ ws) {
  int idx = blockIdx.x * 256 + threadIdx.x;  // 576*256 = 147456 exactly
  if (idx < 131072) {
    const float* __restrict__ src = (idx < 65536) ? W : U;
    int r = idx & 65535;
    int f = r >> 9, lane = (r >> 3) & 63, j = r & 7;
    int kt = f & 3, g = (f >> 2) & 3, w = f >> 4;
    int k = kt * 32 + (lane >> 4) * 8 + j;
    int col = g * 128 + w * 16 + (lane & 15);
    ws[idx] = (bf16)src[k * 512 + col];
  } else {
    int r = idx - 131072;
    int f = r >> 9, lane = (r >> 3) & 63, j = r & 7;
    int kt = f & 3, w = f >> 2;
    int k = kt * 32 + (lane >> 4) * 8 + j;
    int col = w * 16 + (lane & 15);
    ws[idx] = (bf16)NW[k * 128 + col];
  }
}

// ---------------- prep B: features fp32 -> bf16 (streaming) ----------------
__global__ void prep_feats(const float4* __restrict__ in, bf16x8* __restrict__ out) {
  int i = blockIdx.x * 256 + threadIdx.x;
  int stride = gridDim.x * 256;
  for (; i < 1600000; i += stride) {  // 100000*128/8
    float4 a = in[2 * i], b = in[2 * i + 1];
    __builtin_nontemporal_store(pack8(a, b), out + i);
  }
}

// ---------------- fused LSTM aggregator ----------------
__global__ __launch_bounds__(512, 2)
void lstm_kernel(const int* __restrict__ node, const int* __restrict__ neigh,
                 const float* __restrict__ bias, const bf16* __restrict__ wsf,
                 float* __restrict__ out) {
  __shared__ char ub[131072];  // U fragments, frag-linear (copied from ws)
  __shared__ char xb[16384];   // x tile [64 rows][128] bf16, XOR-swizzled
  __shared__ char hb[16384];   // h tile [64 rows][128] bf16, XOR-swizzled

  const int tid  = threadIdx.x;
  const int lane = tid & 63;
  const int ug   = tid >> 6;       // wave = unit group: units [ug*16, ug*16+16)
  const int l15  = lane & 15;
  const int lhi  = lane >> 4;
  const int b0   = blockIdx.x * 64;
  const bf16* __restrict__ fb = wsf + FEATS_OFF;

  // ---- prologue: fill U-frag LDS (straight 128 KB copy, once per block) ----
#pragma unroll
  for (int i = 0; i < 16; ++i) {
    int k = i * 512 + tid;  // 8192 chunks of 16 B
    ((bf16x8*)ub)[k] = *(const bf16x8*)(wsf + 65536 + k * 8);
  }

  float bb[4];
#pragma unroll
  for (int g = 0; g < 4; ++g) bb[g] = bias[g * 128 + ug * 16 + l15];

  f32x4 cc[4];  // cell state: row = m*16 + lhi*4 + r, unit = ug*16 + l15
#pragma unroll
  for (int m = 0; m < 4; ++m) cc[m] = splat4(0.0f);

  // Gather mapping: thread covers row gr, 32 consecutive bytes (16 bf16).
  const int gr = tid >> 3;          // 0..63
  const int gq = tid & 7;           // 32B chunk within row
  const int xsw = (gr & 7) << 4;
  const int xbase = gr * 256 + gq * 32;
  const int rbase = (b0 + gr) * 25;

  // x_0
  {
    int ni = neigh[rbase];
    const bf16* gsrc = fb + (size_t)ni * 128 + gq * 16;
    *(bf16x8*)(xb + (xbase ^ xsw))        = __builtin_nontemporal_load((const bf16x8*)gsrc);
    *(bf16x8*)(xb + ((xbase + 16) ^ xsw)) = __builtin_nontemporal_load((const bf16x8*)(gsrc + 8));
  }
  int ni_next = neigh[rbase + 1];
  __syncthreads();

  f32x4 acc[4][4];                 // [gate][Mtile]
  const int asw = (l15 & 7) << 4;  // A-frag row swizzle (row&7 == l15&7)

  // MFMA phase: W frags already in regs; per kt, 4 U ds_reads + 4 xa (+4 ha)
  // ds_reads + 16 (+16) MFMAs.
  auto mfma_phase = [&](const bf16x8 (&wf)[4][4], bool withH) {
#pragma unroll
    for (int kt = 0; kt < 4; ++kt) {
      bf16x8 ufr[4];
#pragma unroll
      for (int g = 0; g < 4; ++g)
        ufr[g] = *(const bf16x8*)(ub + (((ug * 16 + g * 4 + kt) << 6 | lane) << 4));
      bf16x8 xa[4];
#pragma unroll
      for (int m = 0; m < 4; ++m)
        xa[m] = *(const bf16x8*)(xb + (((m * 16 + l15) * 256 + (kt * 4 + lhi) * 16) ^ asw));
#pragma unroll
      for (int g = 0; g < 4; ++g)
#pragma unroll
        for (int m = 0; m < 4; ++m)
          acc[g][m] = __builtin_amdgcn_mfma_f32_16x16x32_bf16(xa[m], wf[g][kt], acc[g][m], 0, 0, 0);
      if (withH) {
        bf16x8 ha[4];
#pragma unroll
        for (int m = 0; m < 4; ++m)
          ha[m] = *(const bf16x8*)(hb + (((m * 16 + l15) * 256 + (kt * 4 + lhi) * 16) ^ asw));
#pragma unroll
        for (int g = 0; g < 4; ++g)
#pragma unroll
          for (int m = 0; m < 4; ++m)
            acc[g][m] = __builtin_amdgcn_mfma_f32_16x16x32_bf16(ha[m], ufr[g], acc[g][m], 0, 0, 0);
      }
    }
  };

#pragma unroll 1
  for (int t = 0; t < 24; ++t) {
    int ni = ni_next;
    ni_next = (t < 23) ? neigh[rbase + t + 2] : node[b0 + gr];

    // 1. ALL W fragment loads issued first (oldest in vmcnt queue)
    bf16x8 wf[4][4];
#pragma unroll
    for (int g = 0; g < 4; ++g)
#pragma unroll
      for (int kt = 0; kt < 4; ++kt)
        wf[g][kt] = *(const bf16x8*)(wsf + (((ug * 4 + g) * 4 + kt) << 9) + (lane << 3));
    __builtin_amdgcn_sched_barrier(0);  // pin: gather issues AFTER the W loads

    // 2. gather x_{t+1}: youngest in queue; counted vmcnt waits for W leave
    //    it in flight under the whole MFMA phase
    const bf16* gsrc = fb + (size_t)ni * 128 + gq * 16;
    bf16x8 pa = __builtin_nontemporal_load((const bf16x8*)gsrc);
    bf16x8 pb = __builtin_nontemporal_load((const bf16x8*)(gsrc + 8));

    // 3. acc init (VALU only)
#pragma unroll
    for (int g = 0; g < 4; ++g) {
      f32x4 bi = splat4(bb[g]);
#pragma unroll
      for (int m = 0; m < 4; ++m) acc[g][m] = bi;
    }

    // 4. MFMA phase
    if (t == 0) mfma_phase(wf, false); else mfma_phase(wf, true);

    __syncthreads();  // all reads of xb/hb done

    *(bf16x8*)(xb + (xbase ^ xsw))        = pa;
    *(bf16x8*)(xb + ((xbase + 16) ^ xsw)) = pb;

#pragma unroll
    for (int m = 0; m < 4; ++m)
#pragma unroll
      for (int r = 0; r < 4; ++r) {
        float iv = fast_sig(acc[0][m][r]);
        float fv = fast_sig(acc[1][m][r]);
        float gv = fast_tanh(acc[2][m][r]);
        float ov = fast_sig(acc[3][m][r]);
        float cv = fv * cc[m][r] + iv * gv;
        cc[m][r] = cv;
        float hv = ov * fast_tanh(cv);
        int row = m * 16 + lhi * 4 + r;
        *(bf16*)(hb + ((row * 256 + (ug * 16 + l15) * 2) ^ ((row & 7) << 4))) = (bf16)hv;
      }
    __syncthreads();  // new x/h visible
  }

  // ----- step 24 (peeled): gather = NODE features (idx pipelined above) -----
  float hl[4][4];
  {
    bf16x8 wf[4][4];
#pragma unroll
    for (int g = 0; g < 4; ++g)
#pragma unroll
      for (int kt = 0; kt < 4; ++kt)
        wf[g][kt] = *(const bf16x8*)(wsf + (((ug * 4 + g) * 4 + kt) << 9) + (lane << 3));
    __builtin_amdgcn_sched_barrier(0);

    const bf16* gsrc = fb + (size_t)ni_next * 128 + gq * 16;
    bf16x8 pa = __builtin_nontemporal_load((const bf16x8*)gsrc);
    bf16x8 pb = __builtin_nontemporal_load((const bf16x8*)(gsrc + 8));

#pragma unroll
    for (int g = 0; g < 4; ++g) {
      f32x4 bi = splat4(bb[g]);
#pragma unroll
      for (int m = 0; m < 4; ++m) acc[g][m] = bi;
    }
    mfma_phase(wf, true);

    __syncthreads();

    *(bf16x8*)(xb + (xbase ^ xsw))        = pa;  // node feats
    *(bf16x8*)(xb + ((xbase + 16) ^ xsw)) = pb;

#pragma unroll
    for (int m = 0; m < 4; ++m)
#pragma unroll
      for (int r = 0; r < 4; ++r) {
        float iv = fast_sig(acc[0][m][r]);
        float fv = fast_sig(acc[1][m][r]);
        float gv = fast_tanh(acc[2][m][r]);
        float ov = fast_sig(acc[3][m][r]);
        float cv = fv * cc[m][r] + iv * gv;
        hl[m][r] = ov * fast_tanh(cv);
      }
    __syncthreads();  // node feats visible in xb
  }

  // ----- from_self = node_feat @ node_weights; out = relu((s + h)/2) -----
  {
    f32x4 accs[4];
#pragma unroll
    for (int m = 0; m < 4; ++m) accs[m] = splat4(0.0f);
#pragma unroll
    for (int kt = 0; kt < 4; ++kt) {
      bf16x8 nwf = *(const bf16x8*)(wsf + 131072 + ((ug * 4 + kt) << 9) + (lane << 3));
      bf16x8 xa[4];
#pragma unroll
      for (int m = 0; m < 4; ++m)
        xa[m] = *(const bf16x8*)(xb + (((m * 16 + l15) * 256 + (kt * 4 + lhi) * 16) ^ asw));
#pragma unroll
      for (int m = 0; m < 4; ++m)
        accs[m] = __builtin_amdgcn_mfma_f32_16x16x32_bf16(xa[m], nwf, accs[m], 0, 0, 0);
    }
#pragma unroll
    for (int m = 0; m < 4; ++m)
#pragma unroll
      for (int r = 0; r < 4; ++r) {
        int row = m * 16 + lhi * 4 + r;
        float v = (accs[m][r] + hl[m][r]) * 0.5f;
        __builtin_nontemporal_store(v > 0.0f ? v : 0.0f,
                                    out + (b0 + row) * 128 + ug * 16 + l15);
      }
  }
}

extern "C" void kernel_launch(void* const* d_in, const int* in_sizes, int n_in,
                              void* d_out, int out_size, void* d_ws, size_t ws_size,
                              hipStream_t stream) {
  const float* feats = (const float*)d_in[0];   // 100000 x 128
  const int*   node  = (const int*)d_in[1];     // 16384 x 1
  const int*   neigh = (const int*)d_in[2];     // 16384 x 25
  const float* nw    = (const float*)d_in[3];   // 128 x 128
  const float* W     = (const float*)d_in[4];   // 128 x 512
  const float* U     = (const float*)d_in[5];   // 128 x 512
  const float* b     = (const float*)d_in[6];   // 512
  bf16* ws = (bf16*)d_ws;                       // needs 26.2 MB
  float* out = (float*)d_out;                   // 16384 x 128

  prep_kernel<<<576, 256, 0, stream>>>(W, U, nw, ws);
  prep_feats<<<2048, 256, 0, stream>>>((const float4*)feats, (bf16x8*)(ws + FEATS_OFF));
  lstm_kernel<<<256, 512, 0, stream>>>(node, neigh, b, ws, out);
}